// Round 1
// baseline (652.488 us; speedup 1.0000x reference)
//
#include <hip/hip_runtime.h>
#include <hip/hip_bf16.h>

#define NNODES 50000
#define NEDGES 800000
#define F_IN 128
#define F_HID 256

constexpr int SCAN_BLOCKS = (NNODES + 255) / 256;  // 196

// ---------------- workspace layout (bytes) ----------------
constexpr size_t OFF_FLAG   = 0;                       // 256
constexpr size_t OFF_DINV   = 256;                     // 200000 -> 200192
constexpr size_t OFF_ROWPTR = OFF_DINV + 200192;       // 200004 -> 200192
constexpr size_t OFF_CNT    = OFF_ROWPTR + 200192;     // 200000 -> 200192
constexpr size_t OFF_BSUM   = OFF_CNT + 200192;        // 1024
constexpr size_t OFF_BSUMS  = OFF_BSUM + 1024;         // 1024
constexpr size_t OFF_SRC    = OFF_BSUMS + 1024;        // 3200000
constexpr size_t OFF_DST    = OFF_SRC + 3200000;       // 3200000
constexpr size_t OFF_COL    = OFF_DST + 3200000;       // 3200000
constexpr size_t OFF_NORM   = OFF_COL + 3200000;       // 3200000
constexpr size_t OFF_BUF1   = OFF_NORM + 3200000;      // 51200000
// total ~64.6 MB

// ---------------- edge dtype detect / convert ----------------
__global__ void detect_kernel(const unsigned long long* __restrict__ p, int* __restrict__ flag) {
    __shared__ int bad;
    if (threadIdx.x == 0) bad = 0;
    __syncthreads();
    unsigned long long v = p[threadIdx.x];  // first 256 int64 (or 512 int32) of src row
    if (v >= (unsigned long long)NNODES) atomicAdd(&bad, 1);
    __syncthreads();
    if (threadIdx.x == 0) *flag = (bad == 0) ? 1 : 0;  // 1 => data really is int64
}

__global__ __launch_bounds__(256) void convert_kernel(const void* __restrict__ raw,
                                                      const int* __restrict__ flag,
                                                      int* __restrict__ src, int* __restrict__ dst) {
    int e = blockIdx.x * 256 + threadIdx.x;
    if (e >= NEDGES) return;
    if (*flag) {
        const long long* p = (const long long*)raw;
        src[e] = (int)p[e];
        dst[e] = (int)p[NEDGES + e];
    } else {
        const int* p = (const int*)raw;
        src[e] = p[e];
        dst[e] = p[NEDGES + e];
    }
}

// ---------------- degree / normalization ----------------
__global__ __launch_bounds__(256) void count_kernel(const int* __restrict__ dst, int* __restrict__ cnt) {
    int e = blockIdx.x * 256 + threadIdx.x;
    if (e >= NEDGES) return;
    atomicAdd(&cnt[dst[e]], 1);
}

__global__ __launch_bounds__(256) void dinv_kernel(const int* __restrict__ cnt, float* __restrict__ dinv) {
    int i = blockIdx.x * 256 + threadIdx.x;
    if (i >= NNODES) return;
    dinv[i] = rsqrtf((float)cnt[i] + 1.0f);  // +1 for self-loop; deg>=1 always
}

// ---------------- exclusive scan (3 kernels) ----------------
__global__ __launch_bounds__(256) void scan_reduce(const int* __restrict__ cnt, int* __restrict__ bsum) {
    __shared__ int s[256];
    int i = blockIdx.x * 256 + threadIdx.x;
    s[threadIdx.x] = (i < NNODES) ? cnt[i] : 0;
    __syncthreads();
    for (int o = 128; o > 0; o >>= 1) {
        if (threadIdx.x < o) s[threadIdx.x] += s[threadIdx.x + o];
        __syncthreads();
    }
    if (threadIdx.x == 0) bsum[blockIdx.x] = s[0];
}

__global__ __launch_bounds__(256) void scan_top(const int* __restrict__ bsum, int* __restrict__ bsumS) {
    __shared__ int s[256];
    int t = threadIdx.x;
    int v = (t < SCAN_BLOCKS) ? bsum[t] : 0;
    s[t] = v;
    __syncthreads();
    for (int o = 1; o < 256; o <<= 1) {
        int tmp = (t >= o) ? s[t - o] : 0;
        __syncthreads();
        s[t] += tmp;
        __syncthreads();
    }
    if (t < SCAN_BLOCKS) bsumS[t] = s[t] - v;  // exclusive
}

__global__ __launch_bounds__(256) void scan_final(const int* __restrict__ cnt, const int* __restrict__ bsumS,
                                                  int* __restrict__ row_ptr) {
    __shared__ int s[256];
    int t = threadIdx.x;
    int i = blockIdx.x * 256 + t;
    int v = (i < NNODES) ? cnt[i] : 0;
    s[t] = v;
    __syncthreads();
    for (int o = 1; o < 256; o <<= 1) {
        int tmp = (t >= o) ? s[t - o] : 0;
        __syncthreads();
        s[t] += tmp;
        __syncthreads();
    }
    if (i < NNODES) row_ptr[i] = s[t] - v + bsumS[blockIdx.x];
    if (i == 0) row_ptr[NNODES] = NEDGES;
}

// ---------------- CSR fill ----------------
__global__ __launch_bounds__(256) void fill_kernel(const int* __restrict__ src, const int* __restrict__ dst,
                                                   const int* __restrict__ row_ptr, int* __restrict__ fillc,
                                                   const float* __restrict__ dinv,
                                                   int* __restrict__ col, float* __restrict__ normE) {
    int e = blockIdx.x * 256 + threadIdx.x;
    if (e >= NEDGES) return;
    int d = dst[e];
    int s = src[e];
    int p = row_ptr[d] + atomicAdd(&fillc[d], 1);
    col[p] = s;
    normE[p] = dinv[s] * dinv[d];
}

// ---------------- aggregation: out[v] = dinv[v]^2*h[v] + sum_e norm[e]*h[col[e]] ----------------
template <int F>
__global__ __launch_bounds__(256) void agg_kernel(const float* __restrict__ h,
                                                  const int* __restrict__ row_ptr,
                                                  const int* __restrict__ col,
                                                  const float* __restrict__ normE,
                                                  const float* __restrict__ dinv,
                                                  float* __restrict__ outb) {
    constexpr int VEC = F / 64;  // 2 (F=128) or 4 (F=256)
    int lane = threadIdx.x & 63;
    int v = __builtin_amdgcn_readfirstlane((int)(blockIdx.x * 4 + (threadIdx.x >> 6)));
    const size_t lo = (size_t)lane * VEC;

    float acc[VEC];
    float dv = dinv[v];
    {
        const float* p = h + (size_t)v * F + lo;
        float w = dv * dv;
        if constexpr (VEC == 4) {
            float4 t = *(const float4*)p;
            acc[0] = w * t.x; acc[1] = w * t.y; acc[2] = w * t.z; acc[3] = w * t.w;
        } else {
            float2 t = *(const float2*)p;
            acc[0] = w * t.x; acc[1] = w * t.y;
        }
    }
    int e0 = row_ptr[v], e1 = row_ptr[v + 1];
    for (int e = e0; e < e1; ++e) {
        int s = col[e];
        float w = normE[e];
        const float* p = h + (size_t)s * F + lo;
        if constexpr (VEC == 4) {
            float4 t = *(const float4*)p;
            acc[0] += w * t.x; acc[1] += w * t.y; acc[2] += w * t.z; acc[3] += w * t.w;
        } else {
            float2 t = *(const float2*)p;
            acc[0] += w * t.x; acc[1] += w * t.y;
        }
    }
    float* o = outb + (size_t)v * F + lo;
    if constexpr (VEC == 4) {
        float4 t; t.x = acc[0]; t.y = acc[1]; t.z = acc[2]; t.w = acc[3];
        *(float4*)o = t;
    } else {
        float2 t; t.x = acc[0]; t.y = acc[1];
        *(float2*)o = t;
    }
}

// ---------------- fp32 tiled GEMM: out[M x 256] = A[M x KT] @ W[KT x 256] + b (opt relu) ----------------
template <int KT, bool RELU>
__global__ __launch_bounds__(256) void gemm_kernel(const float* __restrict__ A, const float* __restrict__ W,
                                                   const float* __restrict__ bias, float* __restrict__ out,
                                                   int M) {
    constexpr int BM = 128, BN = 128, BK = 16;
    __shared__ float As[BK][BM + 4];
    __shared__ float Bs[BK][BN + 4];
    int tid = threadIdx.x;
    int m0 = blockIdx.x * BM;
    int n0 = blockIdx.y * BN;
    int tx = tid & 15, ty = tid >> 4;

    float acc[8][8] = {};

    int alr = tid >> 1;          // A tile row 0..127
    int alc = (tid & 1) * 8;     // A tile col base (0 or 8)
    int bslot = tid * 2;         // B f4 slot base
    int bkr = bslot >> 5;        // B tile row 0..15
    int bc4 = bslot & 31;        // B f4 col 0..30 (even)

    for (int k0 = 0; k0 < KT; k0 += BK) {
        // global loads (regs)
        float4 a0, a1;
        int gr = m0 + alr;
        if (gr < M) {
            const float* ap = A + (size_t)gr * KT + k0 + alc;
            a0 = *(const float4*)ap;
            a1 = *(const float4*)(ap + 4);
        } else {
            a0 = make_float4(0.f, 0.f, 0.f, 0.f);
            a1 = a0;
        }
        const float* bp = W + (size_t)(k0 + bkr) * 256 + n0 + bc4 * 4;
        float4 b0 = *(const float4*)bp;
        float4 b1 = *(const float4*)(bp + 4);

        __syncthreads();  // previous iteration's LDS reads done
        As[alc + 0][alr] = a0.x; As[alc + 1][alr] = a0.y; As[alc + 2][alr] = a0.z; As[alc + 3][alr] = a0.w;
        As[alc + 4][alr] = a1.x; As[alc + 5][alr] = a1.y; As[alc + 6][alr] = a1.z; As[alc + 7][alr] = a1.w;
        *(float4*)&Bs[bkr][bc4 * 4] = b0;
        *(float4*)&Bs[bkr][bc4 * 4 + 4] = b1;
        __syncthreads();

#pragma unroll
        for (int k = 0; k < BK; ++k) {
            float av[8], bv[8];
            *(float4*)av       = *(const float4*)&As[k][ty * 8];
            *(float4*)(av + 4) = *(const float4*)&As[k][ty * 8 + 4];
            *(float4*)bv       = *(const float4*)&Bs[k][tx * 8];
            *(float4*)(bv + 4) = *(const float4*)&Bs[k][tx * 8 + 4];
#pragma unroll
            for (int i = 0; i < 8; ++i)
#pragma unroll
                for (int j = 0; j < 8; ++j) acc[i][j] += av[i] * bv[j];
        }
    }

    // epilogue: bias (+relu), store
    float b8[8];
    *(float4*)b8       = *(const float4*)(bias + n0 + tx * 8);
    *(float4*)(b8 + 4) = *(const float4*)(bias + n0 + tx * 8 + 4);
#pragma unroll
    for (int i = 0; i < 8; ++i) {
        int gr = m0 + ty * 8 + i;
        if (gr >= M) break;
        float v[8];
#pragma unroll
        for (int j = 0; j < 8; ++j) {
            float t = acc[i][j] + b8[j];
            if (RELU) t = t > 0.f ? t : 0.f;
            v[j] = t;
        }
        float* op = out + (size_t)gr * 256 + n0 + tx * 8;
        *(float4*)op       = *(const float4*)v;
        *(float4*)(op + 4) = *(const float4*)(v + 4);
    }
}

// ---------------- launch ----------------
extern "C" void kernel_launch(void* const* d_in, const int* in_sizes, int n_in,
                              void* d_out, int out_size, void* d_ws, size_t ws_size,
                              hipStream_t stream) {
    const float* x  = (const float*)d_in[0];
    const void* edges = d_in[1];
    const float* W1 = (const float*)d_in[2];
    const float* b1 = (const float*)d_in[3];
    const float* W2 = (const float*)d_in[4];
    const float* b2 = (const float*)d_in[5];
    const float* W3 = (const float*)d_in[6];
    const float* b3 = (const float*)d_in[7];
    float* out = (float*)d_out;

    char* ws = (char*)d_ws;
    int*   flag   = (int*)(ws + OFF_FLAG);
    float* dinv   = (float*)(ws + OFF_DINV);
    int*   rowptr = (int*)(ws + OFF_ROWPTR);
    int*   cnt    = (int*)(ws + OFF_CNT);
    int*   bsum   = (int*)(ws + OFF_BSUM);
    int*   bsumS  = (int*)(ws + OFF_BSUMS);
    int*   src32  = (int*)(ws + OFF_SRC);
    int*   dst32  = (int*)(ws + OFF_DST);
    int*   col    = (int*)(ws + OFF_COL);
    float* normE  = (float*)(ws + OFF_NORM);
    float* buf1   = (float*)(ws + OFF_BUF1);

    const int EB = (NEDGES + 255) / 256;  // 3125

    // edge normalization
    detect_kernel<<<1, 256, 0, stream>>>((const unsigned long long*)edges, flag);
    convert_kernel<<<EB, 256, 0, stream>>>(edges, flag, src32, dst32);

    // degrees + dinv
    hipMemsetAsync(cnt, 0, NNODES * sizeof(int), stream);
    count_kernel<<<EB, 256, 0, stream>>>(dst32, cnt);
    dinv_kernel<<<SCAN_BLOCKS, 256, 0, stream>>>(cnt, dinv);

    // exclusive scan -> row_ptr
    scan_reduce<<<SCAN_BLOCKS, 256, 0, stream>>>(cnt, bsum);
    scan_top<<<1, 256, 0, stream>>>(bsum, bsumS);
    scan_final<<<SCAN_BLOCKS, 256, 0, stream>>>(cnt, bsumS, rowptr);

    // CSR fill
    hipMemsetAsync(cnt, 0, NNODES * sizeof(int), stream);
    fill_kernel<<<EB, 256, 0, stream>>>(src32, dst32, rowptr, cnt, dinv, col, normE);

    const int AGG_GRID = NNODES / 4;  // 12500
    dim3 ggrid((NNODES + 127) / 128, 2);

    // layer 1: buf1 = A_norm @ x ; out(h1) = relu(buf1 @ W1 + b1)
    agg_kernel<F_IN><<<AGG_GRID, 256, 0, stream>>>(x, rowptr, col, normE, dinv, buf1);
    gemm_kernel<F_IN, true><<<ggrid, 256, 0, stream>>>(buf1, W1, b1, out, NNODES);

    // layer 2: buf1 = A_norm @ h1 ; out(h2) = relu(buf1 @ W2 + b2)
    agg_kernel<F_HID><<<AGG_GRID, 256, 0, stream>>>(out, rowptr, col, normE, dinv, buf1);
    gemm_kernel<F_HID, true><<<ggrid, 256, 0, stream>>>(buf1, W2, b2, out, NNODES);

    // layer 3: buf1 = A_norm @ h2 ; out = buf1 @ W3 + b3
    agg_kernel<F_HID><<<AGG_GRID, 256, 0, stream>>>(out, rowptr, col, normE, dinv, buf1);
    gemm_kernel<F_HID, false><<<ggrid, 256, 0, stream>>>(buf1, W3, b3, out, NNODES);
}

// Round 2
// 384.664 us; speedup vs baseline: 1.6963x; 1.6963x over previous
//
#include <hip/hip_runtime.h>
#include <hip/hip_bf16.h>

#define NNODES 50000
#define NEDGES 800000
#define F_IN 128
#define F_HID 256

using u16 = unsigned short;
using f32x4 = __attribute__((ext_vector_type(4))) float;
using s16x8 = __attribute__((ext_vector_type(8))) short;

constexpr int SCAN_BLOCKS = (NNODES + 255) / 256;  // 196

// ---------------- workspace layout (bytes) ----------------
constexpr size_t OFF_FLAG   = 0;          // 256
constexpr size_t OFF_DINV   = 256;        // 200192
constexpr size_t OFF_ROWPTR = 200448;     // 200192
constexpr size_t OFF_CNT    = 400640;     // 200192
constexpr size_t OFF_BSUM   = 600832;     // 1024
constexpr size_t OFF_BSUMS  = 601856;     // 1024
constexpr size_t OFF_SRC    = 602880;     // 3200000
constexpr size_t OFF_DST    = 3802880;    // 3200000
constexpr size_t OFF_COL    = 7002880;    // 3200000
constexpr size_t OFF_NORM   = 10202880;   // 3200000
constexpr size_t OFF_XB     = 13402880;   // 12800000 (50000x128 bf16)
constexpr size_t OFF_HB     = 26202880;   // 25600000 (50000x256 bf16)
constexpr size_t OFF_AGGB   = 51802880;   // 25600000 (50000x256 bf16)
constexpr size_t OFF_W1T    = 77402880;   // 65536  (256x128 bf16, transposed)
constexpr size_t OFF_W2T    = 77468416;   // 131072 (256x256 bf16, transposed)
constexpr size_t OFF_W3T    = 77599488;   // 131072
// total ~77.7 MB

static __device__ __forceinline__ float b2f(u16 u) {
    union { unsigned int i; float f; } v;
    v.i = ((unsigned int)u) << 16;
    return v.f;
}
static __device__ __forceinline__ u16 f2b(float f) {
    __hip_bfloat16 h = __float2bfloat16(f);  // round-to-nearest
    return __builtin_bit_cast(u16, h);
}

// ---------------- edge dtype detect / convert ----------------
__global__ void detect_kernel(const unsigned long long* __restrict__ p, int* __restrict__ flag) {
    __shared__ int bad;
    if (threadIdx.x == 0) bad = 0;
    __syncthreads();
    unsigned long long v = p[threadIdx.x];
    if (v >= (unsigned long long)NNODES) atomicAdd(&bad, 1);
    __syncthreads();
    if (threadIdx.x == 0) *flag = (bad == 0) ? 1 : 0;  // 1 => int64 layout
}

__global__ __launch_bounds__(256) void convert_kernel(const void* __restrict__ raw,
                                                      const int* __restrict__ flag,
                                                      int* __restrict__ src, int* __restrict__ dst) {
    int e = blockIdx.x * 256 + threadIdx.x;
    if (e >= NEDGES) return;
    if (*flag) {
        const long long* p = (const long long*)raw;
        src[e] = (int)p[e];
        dst[e] = (int)p[NEDGES + e];
    } else {
        const int* p = (const int*)raw;
        src[e] = p[e];
        dst[e] = p[NEDGES + e];
    }
}

// ---------------- degree / normalization ----------------
__global__ __launch_bounds__(256) void count_kernel(const int* __restrict__ dst, int* __restrict__ cnt) {
    int e = blockIdx.x * 256 + threadIdx.x;
    if (e >= NEDGES) return;
    atomicAdd(&cnt[dst[e]], 1);
}

__global__ __launch_bounds__(256) void dinv_kernel(const int* __restrict__ cnt, float* __restrict__ dinv) {
    int i = blockIdx.x * 256 + threadIdx.x;
    if (i >= NNODES) return;
    dinv[i] = rsqrtf((float)cnt[i] + 1.0f);  // +1 self-loop
}

// ---------------- exclusive scan (3 kernels) ----------------
__global__ __launch_bounds__(256) void scan_reduce(const int* __restrict__ cnt, int* __restrict__ bsum) {
    __shared__ int s[256];
    int i = blockIdx.x * 256 + threadIdx.x;
    s[threadIdx.x] = (i < NNODES) ? cnt[i] : 0;
    __syncthreads();
    for (int o = 128; o > 0; o >>= 1) {
        if (threadIdx.x < o) s[threadIdx.x] += s[threadIdx.x + o];
        __syncthreads();
    }
    if (threadIdx.x == 0) bsum[blockIdx.x] = s[0];
}

__global__ __launch_bounds__(256) void scan_top(const int* __restrict__ bsum, int* __restrict__ bsumS) {
    __shared__ int s[256];
    int t = threadIdx.x;
    int v = (t < SCAN_BLOCKS) ? bsum[t] : 0;
    s[t] = v;
    __syncthreads();
    for (int o = 1; o < 256; o <<= 1) {
        int tmp = (t >= o) ? s[t - o] : 0;
        __syncthreads();
        s[t] += tmp;
        __syncthreads();
    }
    if (t < SCAN_BLOCKS) bsumS[t] = s[t] - v;
}

__global__ __launch_bounds__(256) void scan_final(const int* __restrict__ cnt, const int* __restrict__ bsumS,
                                                  int* __restrict__ row_ptr) {
    __shared__ int s[256];
    int t = threadIdx.x;
    int i = blockIdx.x * 256 + t;
    int v = (i < NNODES) ? cnt[i] : 0;
    s[t] = v;
    __syncthreads();
    for (int o = 1; o < 256; o <<= 1) {
        int tmp = (t >= o) ? s[t - o] : 0;
        __syncthreads();
        s[t] += tmp;
        __syncthreads();
    }
    if (i < NNODES) row_ptr[i] = s[t] - v + bsumS[blockIdx.x];
    if (i == 0) row_ptr[NNODES] = NEDGES;
}

// ---------------- CSR fill ----------------
__global__ __launch_bounds__(256) void fill_kernel(const int* __restrict__ src, const int* __restrict__ dst,
                                                   const int* __restrict__ row_ptr, int* __restrict__ fillc,
                                                   const float* __restrict__ dinv,
                                                   int* __restrict__ col, float* __restrict__ normE) {
    int e = blockIdx.x * 256 + threadIdx.x;
    if (e >= NEDGES) return;
    int d = dst[e];
    int s = src[e];
    int p = row_ptr[d] + atomicAdd(&fillc[d], 1);
    col[p] = s;
    normE[p] = dinv[s] * dinv[d];
}

// ---------------- fp32 -> bf16 converts ----------------
__global__ __launch_bounds__(256) void x2b_kernel(const float* __restrict__ x, u16* __restrict__ xb) {
    int i = blockIdx.x * 256 + threadIdx.x;  // over float4 units: 50000*128/4 = 1.6e6
    float4 v = ((const float4*)x)[i];
    ushort4 o;
    o.x = f2b(v.x); o.y = f2b(v.y); o.z = f2b(v.z); o.w = f2b(v.w);
    ((ushort4*)xb)[i] = o;
}

// W[K][256] fp32 -> Wt[256][K] bf16
__global__ __launch_bounds__(256) void wt_kernel(const float* __restrict__ W, u16* __restrict__ Wt, int K) {
    int idx = blockIdx.x * 256 + threadIdx.x;
    if (idx >= K * 256) return;
    int k = idx >> 8, n = idx & 255;
    Wt[n * K + k] = f2b(W[idx]);
}

// ---------------- aggregation (bf16 in, fp32 accum, bf16 out) ----------------
template <int F>
__global__ __launch_bounds__(256) void agg_kernel(const u16* __restrict__ h,
                                                  const int* __restrict__ row_ptr,
                                                  const int* __restrict__ col,
                                                  const float* __restrict__ normE,
                                                  const float* __restrict__ dinv,
                                                  u16* __restrict__ outb) {
    constexpr int VEC = F / 64;  // 2 (F=128) or 4 (F=256)
    int lane = threadIdx.x & 63;
    int v = __builtin_amdgcn_readfirstlane((int)(blockIdx.x * 4 + (threadIdx.x >> 6)));
    const size_t lo = (size_t)lane * VEC;

    float acc[VEC];
    float dv = dinv[v];
    {
        const u16* p = h + (size_t)v * F + lo;
        float w = dv * dv;
        if constexpr (VEC == 4) {
            ushort4 t = *(const ushort4*)p;
            acc[0] = w * b2f(t.x); acc[1] = w * b2f(t.y); acc[2] = w * b2f(t.z); acc[3] = w * b2f(t.w);
        } else {
            ushort2 t = *(const ushort2*)p;
            acc[0] = w * b2f(t.x); acc[1] = w * b2f(t.y);
        }
    }
    int e0 = row_ptr[v], e1 = row_ptr[v + 1];
    for (int e = e0; e < e1; ++e) {
        int s = col[e];
        float w = normE[e];
        const u16* p = h + (size_t)s * F + lo;
        if constexpr (VEC == 4) {
            ushort4 t = *(const ushort4*)p;
            acc[0] += w * b2f(t.x); acc[1] += w * b2f(t.y); acc[2] += w * b2f(t.z); acc[3] += w * b2f(t.w);
        } else {
            ushort2 t = *(const ushort2*)p;
            acc[0] += w * b2f(t.x); acc[1] += w * b2f(t.y);
        }
    }
    u16* o = outb + (size_t)v * F + lo;
    if constexpr (VEC == 4) {
        ushort4 t;
        t.x = f2b(acc[0]); t.y = f2b(acc[1]); t.z = f2b(acc[2]); t.w = f2b(acc[3]);
        *(ushort4*)o = t;
    } else {
        ushort2 t;
        t.x = f2b(acc[0]); t.y = f2b(acc[1]);
        *(ushort2*)o = t;
    }
}

// ---------------- bf16 MFMA GEMM: out[M x 256] = A[M x KT] @ W[KT x 256] + b ----------------
// A row-major bf16 [M][KT]; Wt transposed bf16 [256][KT].
// LDS tiles [row][k] bf16, 16B-chunk XOR swizzle: chunk slot = c ^ (row&3).
template <int KT, bool RELU, bool OUT_BF16>
__global__ __launch_bounds__(256) void gemm_mfma(const u16* __restrict__ A, const u16* __restrict__ Wt,
                                                 const float* __restrict__ bias, void* __restrict__ outp,
                                                 int M) {
    constexpr int BM = 128, BN = 128, BK = 32;
    __shared__ __align__(16) u16 As[BM * BK];
    __shared__ __align__(16) u16 Bs[BN * BK];
    const int tid = threadIdx.x;
    const int lane = tid & 63, wid = tid >> 6;
    const int l15 = lane & 15, lhi = lane >> 4;
    const int m0 = blockIdx.x * BM, n0 = blockIdx.y * BN;
    const int wr = (wid >> 1) * 64, wc = (wid & 1) * 64;

    f32x4 acc[4][4] = {};

    const int sr = tid >> 1;        // staging row 0..127
    const int sc2 = (tid & 1) * 2;  // staging chunk base (0 or 2)

    for (int k0 = 0; k0 < KT; k0 += BK) {
        uint4 av0, av1, bv0, bv1;
        int ar = m0 + sr;
        if (ar < M) {
            const uint4* ap = (const uint4*)(A + (size_t)ar * KT + k0 + sc2 * 8);
            av0 = ap[0]; av1 = ap[1];
        } else {
            av0 = make_uint4(0, 0, 0, 0); av1 = av0;
        }
        const uint4* bp = (const uint4*)(Wt + (size_t)(n0 + sr) * KT + k0 + sc2 * 8);
        bv0 = bp[0]; bv1 = bp[1];

        __syncthreads();
        *(uint4*)&As[sr * BK + ((sc2 ^ (sr & 3)) * 8)]       = av0;
        *(uint4*)&As[sr * BK + (((sc2 + 1) ^ (sr & 3)) * 8)] = av1;
        *(uint4*)&Bs[sr * BK + ((sc2 ^ (sr & 3)) * 8)]       = bv0;
        *(uint4*)&Bs[sr * BK + (((sc2 + 1) ^ (sr & 3)) * 8)] = bv1;
        __syncthreads();

        s16x8 af[4], bfr[4];
#pragma unroll
        for (int m = 0; m < 4; ++m) {
            int r = wr + m * 16 + l15;
            af[m] = *(const s16x8*)&As[r * BK + ((lhi ^ (r & 3)) * 8)];
        }
#pragma unroll
        for (int n = 0; n < 4; ++n) {
            int r = wc + n * 16 + l15;
            bfr[n] = *(const s16x8*)&Bs[r * BK + ((lhi ^ (r & 3)) * 8)];
        }
#pragma unroll
        for (int m = 0; m < 4; ++m)
#pragma unroll
            for (int n = 0; n < 4; ++n)
                acc[m][n] = __builtin_amdgcn_mfma_f32_16x16x32_bf16(af[m], bfr[n], acc[m][n], 0, 0, 0);
    }

    // epilogue: C/D layout col = lane&15, row = (lane>>4)*4 + reg
#pragma unroll
    for (int n = 0; n < 4; ++n) {
        int gcol = n0 + wc + n * 16 + l15;
        float bb = bias[gcol];
#pragma unroll
        for (int m = 0; m < 4; ++m) {
            int gr0 = m0 + wr + m * 16 + lhi * 4;
#pragma unroll
            for (int r = 0; r < 4; ++r) {
                int gr = gr0 + r;
                if (gr >= M) continue;
                float vv = acc[m][n][r] + bb;
                if (RELU) vv = vv > 0.f ? vv : 0.f;
                if (OUT_BF16)
                    ((u16*)outp)[(size_t)gr * 256 + gcol] = f2b(vv);
                else
                    ((float*)outp)[(size_t)gr * 256 + gcol] = vv;
            }
        }
    }
}

// ---------------- launch ----------------
extern "C" void kernel_launch(void* const* d_in, const int* in_sizes, int n_in,
                              void* d_out, int out_size, void* d_ws, size_t ws_size,
                              hipStream_t stream) {
    const float* x  = (const float*)d_in[0];
    const void* edges = d_in[1];
    const float* W1 = (const float*)d_in[2];
    const float* b1 = (const float*)d_in[3];
    const float* W2 = (const float*)d_in[4];
    const float* b2 = (const float*)d_in[5];
    const float* W3 = (const float*)d_in[6];
    const float* b3 = (const float*)d_in[7];
    float* out = (float*)d_out;

    char* ws = (char*)d_ws;
    int*   flag   = (int*)(ws + OFF_FLAG);
    float* dinv   = (float*)(ws + OFF_DINV);
    int*   rowptr = (int*)(ws + OFF_ROWPTR);
    int*   cnt    = (int*)(ws + OFF_CNT);
    int*   bsum   = (int*)(ws + OFF_BSUM);
    int*   bsumS  = (int*)(ws + OFF_BSUMS);
    int*   src32  = (int*)(ws + OFF_SRC);
    int*   dst32  = (int*)(ws + OFF_DST);
    int*   col    = (int*)(ws + OFF_COL);
    float* normE  = (float*)(ws + OFF_NORM);
    u16*   xb     = (u16*)(ws + OFF_XB);
    u16*   hb     = (u16*)(ws + OFF_HB);
    u16*   aggb   = (u16*)(ws + OFF_AGGB);
    u16*   W1t    = (u16*)(ws + OFF_W1T);
    u16*   W2t    = (u16*)(ws + OFF_W2T);
    u16*   W3t    = (u16*)(ws + OFF_W3T);

    const int EB = (NEDGES + 255) / 256;  // 3125

    // edge normalization
    detect_kernel<<<1, 256, 0, stream>>>((const unsigned long long*)edges, flag);
    convert_kernel<<<EB, 256, 0, stream>>>(edges, flag, src32, dst32);

    // degrees + dinv
    hipMemsetAsync(cnt, 0, NNODES * sizeof(int), stream);
    count_kernel<<<EB, 256, 0, stream>>>(dst32, cnt);
    dinv_kernel<<<SCAN_BLOCKS, 256, 0, stream>>>(cnt, dinv);

    // exclusive scan -> row_ptr
    scan_reduce<<<SCAN_BLOCKS, 256, 0, stream>>>(cnt, bsum);
    scan_top<<<1, 256, 0, stream>>>(bsum, bsumS);
    scan_final<<<SCAN_BLOCKS, 256, 0, stream>>>(cnt, bsumS, rowptr);

    // CSR fill
    hipMemsetAsync(cnt, 0, NNODES * sizeof(int), stream);
    fill_kernel<<<EB, 256, 0, stream>>>(src32, dst32, rowptr, cnt, dinv, col, normE);

    // bf16 converts
    x2b_kernel<<<(NNODES * F_IN / 4 + 255) / 256, 256, 0, stream>>>(x, xb);
    wt_kernel<<<(F_IN * 256 + 255) / 256, 256, 0, stream>>>(W1, W1t, F_IN);
    wt_kernel<<<(F_HID * 256 + 255) / 256, 256, 0, stream>>>(W2, W2t, F_HID);
    wt_kernel<<<(F_HID * 256 + 255) / 256, 256, 0, stream>>>(W3, W3t, F_HID);

    const int AGG_GRID = NNODES / 4;  // 12500
    dim3 ggrid((NNODES + 127) / 128, 2);

    // layer 1
    agg_kernel<F_IN><<<AGG_GRID, 256, 0, stream>>>(xb, rowptr, col, normE, dinv, aggb);
    gemm_mfma<F_IN, true, true><<<ggrid, 256, 0, stream>>>(aggb, W1t, b1, hb, NNODES);

    // layer 2
    agg_kernel<F_HID><<<AGG_GRID, 256, 0, stream>>>(hb, rowptr, col, normE, dinv, aggb);
    gemm_mfma<F_HID, true, true><<<ggrid, 256, 0, stream>>>(aggb, W2t, b2, hb, NNODES);

    // layer 3
    agg_kernel<F_HID><<<AGG_GRID, 256, 0, stream>>>(hb, rowptr, col, normE, dinv, aggb);
    gemm_mfma<F_HID, false, false><<<ggrid, 256, 0, stream>>>(aggb, W3t, b3, out, NNODES);
}

// Round 3
// 342.808 us; speedup vs baseline: 1.9034x; 1.1221x over previous
//
#include <hip/hip_runtime.h>
#include <hip/hip_bf16.h>

#define NNODES 50000
#define NEDGES 800000
#define F_IN 128
#define F_HID 256

using u16 = unsigned short;
using f32x4 = __attribute__((ext_vector_type(4))) float;
using s16x8 = __attribute__((ext_vector_type(8))) short;

constexpr int SCAN_BLOCKS = (NNODES + 255) / 256;  // 196

// ---------------- workspace layout (bytes) ----------------
constexpr size_t OFF_FLAG   = 0;          // 256
constexpr size_t OFF_DINV   = 256;        // 200192
constexpr size_t OFF_ROWPTR = 200448;     // 200192
constexpr size_t OFF_CNT    = 400640;     // 200192
constexpr size_t OFF_BSUM   = 600832;     // 1024
constexpr size_t OFF_BSUMS  = 601856;     // 1024
constexpr size_t OFF_SRC    = 602880;     // 3200000
constexpr size_t OFF_DST    = 3802880;    // 3200000
constexpr size_t OFF_COL    = 7002880;    // 3200000
constexpr size_t OFF_NORM   = 10202880;   // 3200000
constexpr size_t OFF_XB     = 13402880;   // 12800000 (50000x128 bf16)
constexpr size_t OFF_HB     = 26202880;   // 25600000 (50000x256 bf16)
constexpr size_t OFF_AGGB   = 51802880;   // 25600000 (50000x256 bf16)
constexpr size_t OFF_W1T    = 77402880;   // 65536  (256x128 bf16, transposed)
constexpr size_t OFF_W2T    = 77468416;   // 131072 (256x256 bf16, transposed)
constexpr size_t OFF_W3T    = 77599488;   // 131072
// total ~77.7 MB

static __device__ __forceinline__ float b2f(u16 u) {
    union { unsigned int i; float f; } v;
    v.i = ((unsigned int)u) << 16;
    return v.f;
}
static __device__ __forceinline__ u16 f2b(float f) {
    __hip_bfloat16 h = __float2bfloat16(f);  // round-to-nearest
    return __builtin_bit_cast(u16, h);
}

// ---------------- edge dtype detect ----------------
__global__ void detect_kernel(const unsigned long long* __restrict__ p, int* __restrict__ flag) {
    __shared__ int bad;
    if (threadIdx.x == 0) bad = 0;
    __syncthreads();
    unsigned long long v = p[threadIdx.x];
    if (v >= (unsigned long long)NNODES) atomicAdd(&bad, 1);
    __syncthreads();
    if (threadIdx.x == 0) *flag = (bad == 0) ? 1 : 0;  // 1 => int64 layout
}

// convert + degree count fused
__global__ __launch_bounds__(256) void convert_kernel(const void* __restrict__ raw,
                                                      const int* __restrict__ flag,
                                                      int* __restrict__ src, int* __restrict__ dst,
                                                      int* __restrict__ cnt) {
    int e = blockIdx.x * 256 + threadIdx.x;
    if (e >= NEDGES) return;
    int s, d;
    if (*flag) {
        const long long* p = (const long long*)raw;
        s = (int)p[e];
        d = (int)p[NEDGES + e];
    } else {
        const int* p = (const int*)raw;
        s = p[e];
        d = p[NEDGES + e];
    }
    src[e] = s;
    dst[e] = d;
    atomicAdd(&cnt[d], 1);
}

// ---------------- exclusive scan (3 kernels); dinv fused into reduce ----------------
__global__ __launch_bounds__(256) void scan_reduce(const int* __restrict__ cnt, int* __restrict__ bsum,
                                                   float* __restrict__ dinv) {
    __shared__ int s[256];
    int i = blockIdx.x * 256 + threadIdx.x;
    int c = (i < NNODES) ? cnt[i] : 0;
    if (i < NNODES) dinv[i] = rsqrtf((float)c + 1.0f);  // +1 self-loop
    s[threadIdx.x] = c;
    __syncthreads();
    for (int o = 128; o > 0; o >>= 1) {
        if (threadIdx.x < o) s[threadIdx.x] += s[threadIdx.x + o];
        __syncthreads();
    }
    if (threadIdx.x == 0) bsum[blockIdx.x] = s[0];
}

__global__ __launch_bounds__(256) void scan_top(const int* __restrict__ bsum, int* __restrict__ bsumS) {
    __shared__ int s[256];
    int t = threadIdx.x;
    int v = (t < SCAN_BLOCKS) ? bsum[t] : 0;
    s[t] = v;
    __syncthreads();
    for (int o = 1; o < 256; o <<= 1) {
        int tmp = (t >= o) ? s[t - o] : 0;
        __syncthreads();
        s[t] += tmp;
        __syncthreads();
    }
    if (t < SCAN_BLOCKS) bsumS[t] = s[t] - v;
}

__global__ __launch_bounds__(256) void scan_final(const int* __restrict__ cnt, const int* __restrict__ bsumS,
                                                  int* __restrict__ row_ptr) {
    __shared__ int s[256];
    int t = threadIdx.x;
    int i = blockIdx.x * 256 + t;
    int v = (i < NNODES) ? cnt[i] : 0;
    s[t] = v;
    __syncthreads();
    for (int o = 1; o < 256; o <<= 1) {
        int tmp = (t >= o) ? s[t - o] : 0;
        __syncthreads();
        s[t] += tmp;
        __syncthreads();
    }
    if (i < NNODES) row_ptr[i] = s[t] - v + bsumS[blockIdx.x];
    if (i == 0) row_ptr[NNODES] = NEDGES;
}

// ---------------- CSR fill ----------------
__global__ __launch_bounds__(256) void fill_kernel(const int* __restrict__ src, const int* __restrict__ dst,
                                                   const int* __restrict__ row_ptr, int* __restrict__ fillc,
                                                   const float* __restrict__ dinv,
                                                   int* __restrict__ col, float* __restrict__ normE) {
    int e = blockIdx.x * 256 + threadIdx.x;
    if (e >= NEDGES) return;
    int d = dst[e];
    int s = src[e];
    int p = row_ptr[d] + atomicAdd(&fillc[d], 1);
    col[p] = s;
    normE[p] = dinv[s] * dinv[d];
}

// ---------------- fp32 -> bf16 converts ----------------
__global__ __launch_bounds__(256) void x2b_kernel(const float* __restrict__ x, u16* __restrict__ xb) {
    int i = blockIdx.x * 256 + threadIdx.x;  // over float4 units
    float4 v = ((const float4*)x)[i];
    ushort4 o;
    o.x = f2b(v.x); o.y = f2b(v.y); o.z = f2b(v.z); o.w = f2b(v.w);
    ((ushort4*)xb)[i] = o;
}

// W[K][256] fp32 -> Wt[256][K] bf16
__global__ __launch_bounds__(256) void wt_kernel(const float* __restrict__ W, u16* __restrict__ Wt, int K) {
    int idx = blockIdx.x * 256 + threadIdx.x;
    if (idx >= K * 256) return;
    int k = idx >> 8, n = idx & 255;
    Wt[n * K + k] = f2b(W[idx]);
}

// ---------------- aggregation (bf16 in, fp32 accum, bf16 out), unroll-8 MLP ----------------
template <int F>
__global__ __launch_bounds__(256) void agg_kernel(const u16* __restrict__ h,
                                                  const int* __restrict__ row_ptr,
                                                  const int* __restrict__ col,
                                                  const float* __restrict__ normE,
                                                  const float* __restrict__ dinv,
                                                  u16* __restrict__ outb) {
    constexpr int VEC = F / 64;  // 2 (F=128) or 4 (F=256) bf16 per lane
    int lane = threadIdx.x & 63;
    int v = __builtin_amdgcn_readfirstlane((int)(blockIdx.x * 4 + (threadIdx.x >> 6)));
    const size_t lo = (size_t)lane * VEC;

    float acc[VEC];
    float dv = dinv[v];
    {
        const u16* p = h + (size_t)v * F + lo;
        float w = dv * dv;
        if constexpr (VEC == 4) {
            ushort4 t = *(const ushort4*)p;
            acc[0] = w * b2f(t.x); acc[1] = w * b2f(t.y); acc[2] = w * b2f(t.z); acc[3] = w * b2f(t.w);
        } else {
            ushort2 t = *(const ushort2*)p;
            acc[0] = w * b2f(t.x); acc[1] = w * b2f(t.y);
        }
    }
    const int e0 = row_ptr[v], e1 = row_ptr[v + 1];
    // predicated unroll-8: always issue 8 col/norm and 8 row loads; OOB lanes get w=0
    for (int e = e0; e < e1; e += 8) {
        int   c[8];
        float w[8];
#pragma unroll
        for (int u = 0; u < 8; ++u) {
            int idx = e + u;
            int cl  = idx < e1 ? idx : e1 - 1;   // safe: loop entered only if e1 > e0 >= 0
            c[u] = col[cl];
            w[u] = idx < e1 ? normE[cl] : 0.0f;
        }
        if constexpr (VEC == 4) {
            ushort4 r[8];
#pragma unroll
            for (int u = 0; u < 8; ++u)
                r[u] = *(const ushort4*)(h + (size_t)c[u] * F + lo);
#pragma unroll
            for (int u = 0; u < 8; ++u) {
                acc[0] += w[u] * b2f(r[u].x);
                acc[1] += w[u] * b2f(r[u].y);
                acc[2] += w[u] * b2f(r[u].z);
                acc[3] += w[u] * b2f(r[u].w);
            }
        } else {
            ushort2 r[8];
#pragma unroll
            for (int u = 0; u < 8; ++u)
                r[u] = *(const ushort2*)(h + (size_t)c[u] * F + lo);
#pragma unroll
            for (int u = 0; u < 8; ++u) {
                acc[0] += w[u] * b2f(r[u].x);
                acc[1] += w[u] * b2f(r[u].y);
            }
        }
    }
    u16* o = outb + (size_t)v * F + lo;
    if constexpr (VEC == 4) {
        ushort4 t;
        t.x = f2b(acc[0]); t.y = f2b(acc[1]); t.z = f2b(acc[2]); t.w = f2b(acc[3]);
        *(ushort4*)o = t;
    } else {
        ushort2 t;
        t.x = f2b(acc[0]); t.y = f2b(acc[1]);
        *(ushort2*)o = t;
    }
}

// ---------------- bf16 MFMA GEMM: out[M x 256] = A[M x KT] @ W[KT x 256] + b ----------------
// A row-major bf16 [M][KT]; Wt transposed bf16 [256][KT].
// LDS tiles [row][k] bf16, 16B-chunk XOR swizzle: chunk slot = c ^ (row&3).
template <int KT, bool RELU, bool OUT_BF16>
__global__ __launch_bounds__(256) void gemm_mfma(const u16* __restrict__ A, const u16* __restrict__ Wt,
                                                 const float* __restrict__ bias, void* __restrict__ outp,
                                                 int M) {
    constexpr int BM = 128, BN = 128, BK = 32;
    __shared__ __align__(16) u16 As[BM * BK];
    __shared__ __align__(16) u16 Bs[BN * BK];
    const int tid = threadIdx.x;
    const int lane = tid & 63, wid = tid >> 6;
    const int l15 = lane & 15, lhi = lane >> 4;
    const int m0 = blockIdx.x * BM, n0 = blockIdx.y * BN;
    const int wr = (wid >> 1) * 64, wc = (wid & 1) * 64;

    f32x4 acc[4][4] = {};

    const int sr = tid >> 1;        // staging row 0..127
    const int sc2 = (tid & 1) * 2;  // staging chunk base (0 or 2)

    for (int k0 = 0; k0 < KT; k0 += BK) {
        uint4 av0, av1, bv0, bv1;
        int ar = m0 + sr;
        if (ar < M) {
            const uint4* ap = (const uint4*)(A + (size_t)ar * KT + k0 + sc2 * 8);
            av0 = ap[0]; av1 = ap[1];
        } else {
            av0 = make_uint4(0, 0, 0, 0); av1 = av0;
        }
        const uint4* bp = (const uint4*)(Wt + (size_t)(n0 + sr) * KT + k0 + sc2 * 8);
        bv0 = bp[0]; bv1 = bp[1];

        __syncthreads();
        *(uint4*)&As[sr * BK + ((sc2 ^ (sr & 3)) * 8)]       = av0;
        *(uint4*)&As[sr * BK + (((sc2 + 1) ^ (sr & 3)) * 8)] = av1;
        *(uint4*)&Bs[sr * BK + ((sc2 ^ (sr & 3)) * 8)]       = bv0;
        *(uint4*)&Bs[sr * BK + (((sc2 + 1) ^ (sr & 3)) * 8)] = bv1;
        __syncthreads();

        s16x8 af[4], bfr[4];
#pragma unroll
        for (int m = 0; m < 4; ++m) {
            int r = wr + m * 16 + l15;
            af[m] = *(const s16x8*)&As[r * BK + ((lhi ^ (r & 3)) * 8)];
        }
#pragma unroll
        for (int n = 0; n < 4; ++n) {
            int r = wc + n * 16 + l15;
            bfr[n] = *(const s16x8*)&Bs[r * BK + ((lhi ^ (r & 3)) * 8)];
        }
#pragma unroll
        for (int m = 0; m < 4; ++m)
#pragma unroll
            for (int n = 0; n < 4; ++n)
                acc[m][n] = __builtin_amdgcn_mfma_f32_16x16x32_bf16(af[m], bfr[n], acc[m][n], 0, 0, 0);
    }

    // epilogue: C/D layout col = lane&15, row = (lane>>4)*4 + reg
#pragma unroll
    for (int n = 0; n < 4; ++n) {
        int gcol = n0 + wc + n * 16 + l15;
        float bb = bias[gcol];
#pragma unroll
        for (int m = 0; m < 4; ++m) {
            int gr0 = m0 + wr + m * 16 + lhi * 4;
#pragma unroll
            for (int r = 0; r < 4; ++r) {
                int gr = gr0 + r;
                if (gr >= M) continue;
                float vv = acc[m][n][r] + bb;
                if (RELU) vv = vv > 0.f ? vv : 0.f;
                if (OUT_BF16)
                    ((u16*)outp)[(size_t)gr * 256 + gcol] = f2b(vv);
                else
                    ((float*)outp)[(size_t)gr * 256 + gcol] = vv;
            }
        }
    }
}

// ---------------- launch ----------------
extern "C" void kernel_launch(void* const* d_in, const int* in_sizes, int n_in,
                              void* d_out, int out_size, void* d_ws, size_t ws_size,
                              hipStream_t stream) {
    const float* x  = (const float*)d_in[0];
    const void* edges = d_in[1];
    const float* W1 = (const float*)d_in[2];
    const float* b1 = (const float*)d_in[3];
    const float* W2 = (const float*)d_in[4];
    const float* b2 = (const float*)d_in[5];
    const float* W3 = (const float*)d_in[6];
    const float* b3 = (const float*)d_in[7];
    float* out = (float*)d_out;

    char* ws = (char*)d_ws;
    int*   flag   = (int*)(ws + OFF_FLAG);
    float* dinv   = (float*)(ws + OFF_DINV);
    int*   rowptr = (int*)(ws + OFF_ROWPTR);
    int*   cnt    = (int*)(ws + OFF_CNT);
    int*   bsum   = (int*)(ws + OFF_BSUM);
    int*   bsumS  = (int*)(ws + OFF_BSUMS);
    int*   src32  = (int*)(ws + OFF_SRC);
    int*   dst32  = (int*)(ws + OFF_DST);
    int*   col    = (int*)(ws + OFF_COL);
    float* normE  = (float*)(ws + OFF_NORM);
    u16*   xb     = (u16*)(ws + OFF_XB);
    u16*   hb     = (u16*)(ws + OFF_HB);
    u16*   aggb   = (u16*)(ws + OFF_AGGB);
    u16*   W1t    = (u16*)(ws + OFF_W1T);
    u16*   W2t    = (u16*)(ws + OFF_W2T);
    u16*   W3t    = (u16*)(ws + OFF_W3T);

    const int EB = (NEDGES + 255) / 256;  // 3125

    // edge normalization + degree count (fused)
    hipMemsetAsync(cnt, 0, NNODES * sizeof(int), stream);
    detect_kernel<<<1, 256, 0, stream>>>((const unsigned long long*)edges, flag);
    convert_kernel<<<EB, 256, 0, stream>>>(edges, flag, src32, dst32, cnt);

    // exclusive scan -> row_ptr (+dinv fused into reduce)
    scan_reduce<<<SCAN_BLOCKS, 256, 0, stream>>>(cnt, bsum, dinv);
    scan_top<<<1, 256, 0, stream>>>(bsum, bsumS);
    scan_final<<<SCAN_BLOCKS, 256, 0, stream>>>(cnt, bsumS, rowptr);

    // CSR fill
    hipMemsetAsync(cnt, 0, NNODES * sizeof(int), stream);
    fill_kernel<<<EB, 256, 0, stream>>>(src32, dst32, rowptr, cnt, dinv, col, normE);

    // bf16 converts
    x2b_kernel<<<(NNODES * F_IN / 4 + 255) / 256, 256, 0, stream>>>(x, xb);
    wt_kernel<<<(F_IN * 256 + 255) / 256, 256, 0, stream>>>(W1, W1t, F_IN);
    wt_kernel<<<(F_HID * 256 + 255) / 256, 256, 0, stream>>>(W2, W2t, F_HID);
    wt_kernel<<<(F_HID * 256 + 255) / 256, 256, 0, stream>>>(W3, W3t, F_HID);

    const int AGG_GRID = NNODES / 4;  // 12500
    dim3 ggrid((NNODES + 127) / 128, 2);

    // layer 1
    agg_kernel<F_IN><<<AGG_GRID, 256, 0, stream>>>(xb, rowptr, col, normE, dinv, aggb);
    gemm_mfma<F_IN, true, true><<<ggrid, 256, 0, stream>>>(aggb, W1t, b1, hb, NNODES);

    // layer 2
    agg_kernel<F_HID><<<AGG_GRID, 256, 0, stream>>>(hb, rowptr, col, normE, dinv, aggb);
    gemm_mfma<F_HID, true, true><<<ggrid, 256, 0, stream>>>(aggb, W2t, b2, hb, NNODES);

    // layer 3
    agg_kernel<F_HID><<<AGG_GRID, 256, 0, stream>>>(hb, rowptr, col, normE, dinv, aggb);
    gemm_mfma<F_HID, false, false><<<ggrid, 256, 0, stream>>>(aggb, W3t, b3, out, NNODES);
}